// Round 5
// baseline (284.048 us; speedup 1.0000x reference)
//
#include <hip/hip_runtime.h>
#include <math.h>

// PrimitiveTokenizer round 5:
//  prep:       4 weight matrices -> bf16 hi/lo MFMA B-fragment planes (as R4).
//  scan_count: per 1024-slot quarter: per-row per-kind counts (cnt_f, den) and
//              per-(window,kind,quarter) totals (int, deterministic).
//  scan_fill:  per quarter: deterministic ballot-ranked compaction into global
//              per-(window=4096,kind) slot lists, tail padded to x64 with 0xFFFF.
//  mlp_kernel: one block per (window,kind). w1[k] hi/lo staged ONCE in LDS.
//              Loop M-tiles of 64 slots: FF -> LDS A-tile -> MFMA (LDS-only
//              operands) -> gelu -> LDS fp32 atomic pool[64 rows][256] ->
//              plain-store flush to poolf (block-exclusive, no global atomics).
//  fuse:       unchanged from R4 (GEMM2 batched over kinds + fuse MLP).

// ws layout (short element offsets for frag planes; byte offsets otherwise)
#define W2F_HI   0
#define W2F_LO   524288
#define W1F_HI   1048576
#define W1F_LO   1179648
#define FW1F_HI  1310720
#define FW1F_LO  1507328
#define FW2F_HI  1703936
#define FW2F_LO  1769472
#define POOL_BYTE 3670016ull
#define CNT_BYTE  37224448ull
#define DEN_BYTE  37355520ull
#define LIST_BYTE 37371904ull
#define QCNT_BYTE 38420480ull

typedef __attribute__((ext_vector_type(8))) short frag;
typedef __attribute__((ext_vector_type(4))) float f32x4;

__device__ __forceinline__ unsigned short f2bf_rn(float x) {
    unsigned int u = __float_as_uint(x);
    unsigned int r = (u + 0x7fffu + ((u >> 16) & 1u)) >> 16;
    return (unsigned short)r;
}
__device__ __forceinline__ float bf2f(unsigned short h) {
    return __uint_as_float(((unsigned int)h) << 16);
}
__device__ __forceinline__ void split_bf(float x, unsigned short& h, unsigned short& l) {
    unsigned short hh = f2bf_rn(x);
    h = hh;
    l = f2bf_rn(x - bf2f(hh));
}

// |abs err| <= ~1.5e-7 (A&S 7.1.26 erf)
__device__ __forceinline__ float gelu_fast(float x) {
    float u = fabsf(x) * 0.7071067811865476f;
    float t = __builtin_amdgcn_rcpf(fmaf(0.3275911f, u, 1.0f));
    float p = fmaf(fmaf(fmaf(fmaf(1.061405429f, t, -1.453152027f), t,
                             1.421413741f), t, -0.284496736f), t, 0.254829592f) * t;
    float e = __expf(-u * u);
    float er = fmaf(-p, e, 1.0f);
    er = copysignf(er, x);
    return 0.5f * x * (1.0f + er);
}

// ---------------- prep: weights -> bf16 hi/lo fragment planes ----------------
__global__ __launch_bounds__(512) void prep_kernel(
    const float* __restrict__ w1, const float* __restrict__ w2,
    const float* __restrict__ fw1, const float* __restrict__ fw2,
    short* __restrict__ ws)
{
    int tid = blockIdx.x * 512 + threadIdx.x;
    int fid = tid >> 6, ln = tid & 63;
    if (fid >= 1792) return;
    int lr = ln & 15, kq = ln >> 4;
    float v[8];
    int dhi, dlo, dsto;
    if (fid < 1024) {                       // w2: [8k][8kst][16nt]
        int k = fid >> 7, kst = (fid >> 4) & 7, nt = fid & 15;
        int col = nt * 16 + lr;
        #pragma unroll
        for (int b = 0; b < 8; ++b) {
            int kg = kst * 32 + kq * 8 + b;
            v[b] = w2[(k * 256 + kg) * 256 + col];
        }
        dsto = fid * 512 + ln * 8; dhi = W2F_HI; dlo = W2F_LO;
    } else if (fid < 1280) {                // w1: [8k][2kst][16nt], K pad 48->64
        int f = fid - 1024;
        int k = f >> 5, kst = (f >> 4) & 1, nt = f & 15;
        int col = nt * 16 + lr;
        #pragma unroll
        for (int b = 0; b < 8; ++b) {
            int kg = kst * 32 + kq * 8 + b;
            v[b] = (kg < 48) ? w1[(k * 48 + kg) * 256 + col] : 0.0f;
        }
        dsto = f * 512 + ln * 8; dhi = W1F_HI; dlo = W1F_LO;
    } else if (fid < 1664) {                // fw1: [24kst][16nt]
        int f = fid - 1280;
        int kst = f >> 4, nt = f & 15;
        int col = nt * 16 + lr;
        #pragma unroll
        for (int b = 0; b < 8; ++b) {
            int kg = kst * 32 + kq * 8 + b;
            v[b] = fw1[kg * 256 + col];
        }
        dsto = f * 512 + ln * 8; dhi = FW1F_HI; dlo = FW1F_LO;
    } else {                                // fw2: [8kst][16nt]
        int f = fid - 1664;
        int kst = f >> 4, nt = f & 15;
        int col = nt * 16 + lr;
        #pragma unroll
        for (int b = 0; b < 8; ++b) {
            int kg = kst * 32 + kq * 8 + b;
            v[b] = fw2[kg * 256 + col];
        }
        dsto = f * 512 + ln * 8; dhi = FW2F_HI; dlo = FW2F_LO;
    }
    union { unsigned short u[8]; frag f; } hu, lu;
    #pragma unroll
    for (int b = 0; b < 8; ++b) split_bf(v[b], hu.u[b], lu.u[b]);
    *(frag*)(ws + dhi + dsto) = hu.f;
    *(frag*)(ws + dlo + dsto) = lu.f;
}

// ---------------- scan pass 1: counts ----------------
// block = 1024 slots (16 rows); b -> window w=b>>2, quarter q=b&3.
__global__ __launch_bounds__(256) void scan_count(
    const int* __restrict__ kinds, const int* __restrict__ mask,
    float* __restrict__ cntf, float* __restrict__ denf,
    int* __restrict__ qcnt)
{
    __shared__ int qc[8];
    const int t = threadIdx.x, b = blockIdx.x;
    const int wv = t >> 6, ln = t & 63;
    if (t < 8) qc[t] = 0;
    __syncthreads();

    for (int j = 0; j < 4; ++j) {
        int R = b * 16 + wv * 4 + j;
        int kd = kinds[R * 64 + ln];
        int mk = mask[R * 64 + ln];
        unsigned long long mb = __ballot(mk != 0);
        int tot = __popcll(mb);
        int myc = 0;
        #pragma unroll
        for (int k = 0; k < 8; ++k) {
            unsigned long long bal = __ballot(mk && (kd == k));
            int c = __popcll(bal);
            myc = (ln == k) ? c : myc;
        }
        if (ln < 8) {
            cntf[R * 8 + ln] = (float)myc;
            atomicAdd(&qc[ln], myc);
        }
        if (ln == 0) denf[R] = 1.0f / (float)(tot > 0 ? tot : 1);
    }
    __syncthreads();
    if (t < 8) qcnt[b * 8 + t] = qc[t];
}

// ---------------- scan pass 2: fill lists ----------------
// block = same quarter; 4 waves x 2 kinds each; deterministic order.
__global__ __launch_bounds__(256) void scan_fill(
    const int* __restrict__ kinds, const int* __restrict__ mask,
    const int* __restrict__ qcnt, unsigned short* __restrict__ listb)
{
    const int t = threadIdx.x, b = blockIdx.x;
    const int w = b >> 2, q = b & 3;
    const int wv = t >> 6, ln = t & 63;
    const unsigned long long below = (1ull << ln) - 1ull;

    for (int half = 0; half < 2; ++half) {
        const int k = wv * 2 + half;
        int base = 0;
        for (int qq = 0; qq < q; ++qq) base += qcnt[(w * 4 + qq) * 8 + k];
        int fill = 0;
        unsigned short* lp = listb + (w * 8 + k) * 1024;
        for (int c = 0; c < 16; ++c) {
            int p = q * 1024 + c * 64 + ln;           // window-local slot id
            int kd = kinds[w * 4096 + p];
            int mk = mask[w * 4096 + p];
            unsigned long long bal = __ballot(mk && (kd == k));
            if (mk && (kd == k)) {
                int rank = __popcll(bal & below);
                int idx = base + fill + rank;
                if (idx < 1024) lp[idx] = (unsigned short)p;
            }
            fill += __popcll(bal);
        }
        if (q == 3) {
            int len = base + fill;                    // total for (w,k)
            int lp64 = (len + 63) & ~63;
            for (int i = len + ln; i < lp64 && i < 1024; i += 64) lp[i] = 0xFFFFu;
        }
    }
}

// ---------------- mlp kernel: one block per (window, kind) ----------------
__global__ __launch_bounds__(512) void mlp_kernel(
    const float* __restrict__ values, const short* __restrict__ wsf,
    const unsigned short* __restrict__ listb, const int* __restrict__ qcnt,
    const float* __restrict__ B_ff, const float* __restrict__ b1,
    float* __restrict__ poolf)
{
    __shared__ __align__(16) short Bhi[16384], Blo[16384];  // 64 KB: w1[k] frags
    __shared__ __align__(16) short At[2][4096];             // 16 KB: A-tile hi/lo
    __shared__ float pool[64 * 257];                        // 65.8 KB
    __shared__ unsigned short e_tile[64];
    __shared__ float Bs[24];

    const int t = threadIdx.x, blk = blockIdx.x;
    const int w = blk >> 3, k = blk & 7;
    const int wv = t >> 6, ln = t & 63, lr16 = ln & 15, kq = ln >> 4;
    const int mt = wv >> 1, nh = wv & 1;

    // stage w1[k] hi/lo -> LDS (once per block)
    {
        const uint4* gh = (const uint4*)(wsf + W1F_HI + k * 16384);
        const uint4* gl = (const uint4*)(wsf + W1F_LO + k * 16384);
        uint4* sh = (uint4*)Bhi;
        uint4* sl = (uint4*)Blo;
        #pragma unroll
        for (int i = 0; i < 4; ++i) {
            sh[t + i * 512] = gh[t + i * 512];
            sl[t + i * 512] = gl[t + i * 512];
        }
    }
    if (t < 24) Bs[t] = B_ff[t];
    for (int i = t; i < 64 * 257; i += 512) pool[i] = 0.0f;

    int len = 0;
    #pragma unroll
    for (int qq = 0; qq < 4; ++qq) len += qcnt[(w * 4 + qq) * 8 + k];
    const int ntl = (len + 63) >> 6;

    // b1 for this wave's 8 column tiles
    float b1r[8];
    #pragma unroll
    for (int n = 0; n < 8; ++n) b1r[n] = b1[k * 256 + (nh * 8 + n) * 16 + lr16];

    __syncthreads();

    for (int m = 0; m < ntl; ++m) {
        // ---- FF phase: A-tile [64 slots][64 feats] bf16 hi/lo, xor-swizzled ----
        {
            int s = t >> 3, g = t & 7;
            unsigned short e = listb[(w * 8 + k) * 1024 + m * 64 + s];
            if (g == 0) e_tile[s] = e;
            union { unsigned short u[8]; frag f; } hu, lu;
            if (g < 6 && e != 0xFFFFu) {
                float v = values[w * 4096 + e];
                int iscos = (g >= 3);
                int j0 = (iscos ? (g - 3) : g) * 8;
                #pragma unroll
                for (int bb = 0; bb < 8; ++bb) {
                    float rev = __builtin_amdgcn_fractf(v * Bs[j0 + bb]);
                    float sv = iscos ? __builtin_amdgcn_cosf(rev)
                                     : __builtin_amdgcn_sinf(rev);
                    split_bf(sv, hu.u[bb], lu.u[bb]);
                }
            } else {
                #pragma unroll
                for (int bb = 0; bb < 8; ++bb) { hu.u[bb] = 0; lu.u[bb] = 0; }
            }
            int ao = s * 64 + ((g ^ (s & 7)) << 3);
            *(frag*)&At[0][ao] = hu.f;
            *(frag*)&At[1][ao] = lu.f;
        }
        __syncthreads();

        // ---- MFMA phase: wave = (mt rows x nh col-half) ----
        frag ah[2], al[2];
        #pragma unroll
        for (int kst = 0; kst < 2; ++kst) {
            int gi = kst * 4 + kq;
            int ao = (mt * 16 + lr16) * 64 + ((gi ^ (lr16 & 7)) << 3);
            ah[kst] = *(const frag*)&At[0][ao];
            al[kst] = *(const frag*)&At[1][ao];
        }
        unsigned short e4[4];
        #pragma unroll
        for (int r = 0; r < 4; ++r) e4[r] = e_tile[mt * 16 + kq * 4 + r];

        #pragma unroll
        for (int n = 0; n < 8; ++n) {
            int nt = nh * 8 + n;
            int o0 = (0 * 16 + nt) * 512 + ln * 8;
            int o1 = (1 * 16 + nt) * 512 + ln * 8;
            frag bh0 = *(const frag*)(Bhi + o0);
            frag bl0 = *(const frag*)(Blo + o0);
            frag bh1 = *(const frag*)(Bhi + o1);
            frag bl1 = *(const frag*)(Blo + o1);
            f32x4 acc = (f32x4)0.0f;
            acc = __builtin_amdgcn_mfma_f32_16x16x32_bf16(ah[0], bh0, acc, 0, 0, 0);
            acc = __builtin_amdgcn_mfma_f32_16x16x32_bf16(al[0], bh0, acc, 0, 0, 0);
            acc = __builtin_amdgcn_mfma_f32_16x16x32_bf16(ah[0], bl0, acc, 0, 0, 0);
            acc = __builtin_amdgcn_mfma_f32_16x16x32_bf16(ah[1], bh1, acc, 0, 0, 0);
            acc = __builtin_amdgcn_mfma_f32_16x16x32_bf16(al[1], bh1, acc, 0, 0, 0);
            acc = __builtin_amdgcn_mfma_f32_16x16x32_bf16(ah[1], bl1, acc, 0, 0, 0);
            #pragma unroll
            for (int r = 0; r < 4; ++r) {
                unsigned short e = e4[r];
                if (e != 0xFFFFu) {
                    float g = gelu_fast(acc[r] + b1r[n]);
                    atomicAdd(&pool[(e >> 6) * 257 + nt * 16 + lr16], g);
                }
            }
        }
        __syncthreads();
    }

    // flush pool (block-exclusive -> plain stores)
    for (int i = t; i < 64 * 256; i += 512) {
        int r = i >> 8, c = i & 255;
        poolf[((size_t)k * 4096 + w * 64 + r) * 256 + c] = pool[r * 257 + c];
    }
}

// ---------------- fuse kernel (unchanged from R4) ----------------
__global__ __launch_bounds__(512) void fuse_kernel(
    const short* __restrict__ ws, const float* __restrict__ poolf,
    const float* __restrict__ cntf, const float* __restrict__ denf,
    const int* __restrict__ pt, const int* __restrict__ lid,
    const float* __restrict__ meta, const float* __restrict__ type_emb,
    const float* __restrict__ layer_emb, const float* __restrict__ b2,
    const float* __restrict__ kind_emb, const float* __restrict__ fb1,
    const float* __restrict__ fb2, const float* __restrict__ meta_w,
    const float* __restrict__ meta_b, float* __restrict__ out)
{
    __shared__ __align__(16) short Af[2][2][4096];
    __shared__ __align__(16) float hz[4096];
    __shared__ float cnt_s[128], den_s[16], meta_s[64];
    __shared__ int pt_s[16], lid_s[16];

    const short* w2f_hi  = ws + W2F_HI;
    const short* w2f_lo  = ws + W2F_LO;
    const short* fw1f_hi = ws + FW1F_HI;
    const short* fw1f_lo = ws + FW1F_LO;
    const short* fw2f_hi = ws + FW2F_HI;
    const short* fw2f_lo = ws + FW2F_LO;

    const int t = threadIdx.x, blk = blockIdx.x, rb = blk * 16;
    const int wv = t >> 6, ln = t & 63, lr16 = ln & 15, kq = ln >> 4;

    if (t < 16) { pt_s[t] = pt[rb + t]; lid_s[t] = lid[rb + t]; den_s[t] = denf[rb + t]; }
    else if (t < 144) cnt_s[t - 16] = cntf[rb * 8 + (t - 16)];
    else if (t < 208) meta_s[t - 144] = meta[rb * 4 + (t - 144)];

    const int sr = t >> 5, sg = t & 31;
    const int skst = sg >> 2, skq = sg & 3;
    const int slane = skq * 16 + sr;
    const int sdst = slane * 64 + ((skst ^ (sr & 7)) << 3);

    auto stage = [&](int k, int buf) {
        const float* src = poolf + ((size_t)k * 4096 + rb + sr) * 256 + sg * 8;
        f32x4 u0 = *(const f32x4*)src;
        f32x4 u1 = *(const f32x4*)(src + 4);
        union { unsigned short u[8]; frag f; } hu, lu;
        #pragma unroll
        for (int b = 0; b < 4; ++b) {
            split_bf(u0[b], hu.u[b], lu.u[b]);
            split_bf(u1[b], hu.u[b + 4], lu.u[b + 4]);
        }
        *(frag*)&Af[buf][0][sdst] = hu.f;
        *(frag*)&Af[buf][1][sdst] = lu.f;
    };

    stage(0, 0);
    __syncthreads();

    f32x4 acc[2];
    acc[0] = (f32x4)0.0f; acc[1] = (f32x4)0.0f;

    for (int k = 0; k < 8; ++k) {
        const int buf = k & 1;
        if (k < 7) stage(k + 1, buf ^ 1);
        #pragma unroll 2
        for (int kst = 0; kst < 8; ++kst) {
            int ao = ln * 64 + ((kst ^ (ln & 7)) << 3);
            frag ah = *(const frag*)&Af[buf][0][ao];
            frag al = *(const frag*)&Af[buf][1][ao];
            #pragma unroll
            for (int n = 0; n < 2; ++n) {
                size_t bo = (((size_t)k * 8 + kst) * 16 + (wv * 2 + n)) * 512 + ln * 8;
                frag bh = *(const frag*)(w2f_hi + bo);
                frag bl = *(const frag*)(w2f_lo + bo);
                acc[n] = __builtin_amdgcn_mfma_f32_16x16x32_bf16(ah, bh, acc[n], 0, 0, 0);
                acc[n] = __builtin_amdgcn_mfma_f32_16x16x32_bf16(al, bh, acc[n], 0, 0, 0);
                acc[n] = __builtin_amdgcn_mfma_f32_16x16x32_bf16(ah, bl, acc[n], 0, 0, 0);
            }
        }
        __syncthreads();
    }

    #pragma unroll
    for (int n = 0; n < 2; ++n) {
        int col = (wv * 2 + n) * 16 + lr16;
        float bks[8];
        #pragma unroll
        for (int k = 0; k < 8; ++k) bks[k] = b2[k * 256 + col] + kind_emb[k * 256 + col];
        #pragma unroll
        for (int r = 0; r < 4; ++r) {
            int row = kq * 4 + r;
            float hv = acc[n][r];
            #pragma unroll
            for (int k = 0; k < 8; ++k) hv = fmaf(cnt_s[row * 8 + k], bks[k], hv);
            hv *= den_s[row];
            hz[row * 256 + ((((col >> 2) ^ (row & 7)) << 2) | (col & 3))] = hv;
        }
    }
    __syncthreads();

    f32x4 az[2];
    az[0] = (f32x4)0.0f; az[1] = (f32x4)0.0f;

    for (int kst = 0; kst < 24; ++kst) {
        const int row = lr16;
        union { unsigned short u[8]; frag f; } hu, lu;
        if (kst < 8) {
            int c0 = kst * 8 + kq * 2;
            f32x4 u0 = *(const f32x4*)&hz[row * 256 + ((c0 ^ (row & 7)) << 2)];
            f32x4 u1 = *(const f32x4*)&hz[row * 256 + (((c0 + 1) ^ (row & 7)) << 2)];
            #pragma unroll
            for (int b = 0; b < 4; ++b) {
                split_bf(u0[b], hu.u[b], lu.u[b]);
                split_bf(u1[b], hu.u[b + 4], lu.u[b + 4]);
            }
        } else {
            const float* eb = (kst < 16) ? type_emb : layer_emb;
            const int* ids = (kst < 16) ? pt_s : lid_s;
            int ko = (kst & 7) * 32 + kq * 8;
            const float* sp = eb + (size_t)ids[row] * 256 + ko;
            f32x4 u0 = *(const f32x4*)sp;
            f32x4 u1 = *(const f32x4*)(sp + 4);
            #pragma unroll
            for (int b = 0; b < 4; ++b) {
                split_bf(u0[b], hu.u[b], lu.u[b]);
                split_bf(u1[b], hu.u[b + 4], lu.u[b + 4]);
            }
        }
        frag ah = hu.f, al = lu.f;
        #pragma unroll
        for (int n = 0; n < 2; ++n) {
            size_t bo = ((size_t)kst * 16 + (wv * 2 + n)) * 512 + ln * 8;
            frag bh = *(const frag*)(fw1f_hi + bo);
            frag bl = *(const frag*)(fw1f_lo + bo);
            az[n] = __builtin_amdgcn_mfma_f32_16x16x32_bf16(ah, bh, az[n], 0, 0, 0);
            az[n] = __builtin_amdgcn_mfma_f32_16x16x32_bf16(al, bh, az[n], 0, 0, 0);
            az[n] = __builtin_amdgcn_mfma_f32_16x16x32_bf16(ah, bl, az[n], 0, 0, 0);
        }
    }
    __syncthreads();

    #pragma unroll
    for (int n = 0; n < 2; ++n) {
        int col = (wv * 2 + n) * 16 + lr16;
        float fb1v = fb1[col];
        #pragma unroll
        for (int r = 0; r < 4; ++r) {
            int row = kq * 4 + r;
            float z = gelu_fast(az[n][r] + fb1v);
            hz[row * 256 + ((((col >> 2) ^ (row & 7)) << 2) | (col & 3))] = z;
        }
    }
    __syncthreads();

    f32x4 ao2[2];
    ao2[0] = (f32x4)0.0f; ao2[1] = (f32x4)0.0f;

    for (int kst = 0; kst < 8; ++kst) {
        const int row = lr16;
        int c0 = kst * 8 + kq * 2;
        f32x4 u0 = *(const f32x4*)&hz[row * 256 + ((c0 ^ (row & 7)) << 2)];
        f32x4 u1 = *(const f32x4*)&hz[row * 256 + (((c0 + 1) ^ (row & 7)) << 2)];
        union { unsigned short u[8]; frag f; } hu, lu;
        #pragma unroll
        for (int b = 0; b < 4; ++b) {
            split_bf(u0[b], hu.u[b], lu.u[b]);
            split_bf(u1[b], hu.u[b + 4], lu.u[b + 4]);
        }
        frag ah = hu.f, al = lu.f;
        #pragma unroll
        for (int n = 0; n < 2; ++n) {
            size_t bo = ((size_t)kst * 16 + (wv * 2 + n)) * 512 + ln * 8;
            frag bh = *(const frag*)(fw2f_hi + bo);
            frag bl = *(const frag*)(fw2f_lo + bo);
            ao2[n] = __builtin_amdgcn_mfma_f32_16x16x32_bf16(ah, bh, ao2[n], 0, 0, 0);
            ao2[n] = __builtin_amdgcn_mfma_f32_16x16x32_bf16(al, bh, ao2[n], 0, 0, 0);
            ao2[n] = __builtin_amdgcn_mfma_f32_16x16x32_bf16(ah, bl, ao2[n], 0, 0, 0);
        }
    }

    #pragma unroll
    for (int n = 0; n < 2; ++n) {
        int col = (wv * 2 + n) * 16 + lr16;
        float ob = fb2[col] + meta_b[col];
        float mw0 = meta_w[col], mw1 = meta_w[256 + col];
        float mw2 = meta_w[512 + col], mw3 = meta_w[768 + col];
        #pragma unroll
        for (int r = 0; r < 4; ++r) {
            int row = kq * 4 + r;
            float o = ao2[n][r] + ob;
            o = fmaf(meta_s[row * 4 + 0], mw0, o);
            o = fmaf(meta_s[row * 4 + 1], mw1, o);
            o = fmaf(meta_s[row * 4 + 2], mw2, o);
            o = fmaf(meta_s[row * 4 + 3], mw3, o);
            out[(size_t)(rb + row) * 256 + col] = o;
        }
    }
}

extern "C" void kernel_launch(void* const* d_in, const int* in_sizes, int n_in,
                              void* d_out, int out_size, void* d_ws, size_t ws_size,
                              hipStream_t stream) {
    const float* values    = (const float*)d_in[0];
    const int*   kinds     = (const int*)d_in[1];
    const int*   mask      = (const int*)d_in[2];
    const int*   prim_type = (const int*)d_in[3];
    const int*   layer_id  = (const int*)d_in[4];
    const float* meta      = (const float*)d_in[5];
    const float* B_ff      = (const float*)d_in[6];
    const float* kind_emb  = (const float*)d_in[7];
    const float* type_emb  = (const float*)d_in[8];
    const float* layer_emb = (const float*)d_in[9];
    const float* mlp_w1    = (const float*)d_in[10];
    const float* mlp_b1    = (const float*)d_in[11];
    const float* mlp_w2    = (const float*)d_in[12];
    const float* mlp_b2    = (const float*)d_in[13];
    const float* fuse_w1   = (const float*)d_in[14];
    const float* fuse_b1   = (const float*)d_in[15];
    const float* fuse_w2   = (const float*)d_in[16];
    const float* fuse_b2   = (const float*)d_in[17];
    const float* meta_w    = (const float*)d_in[18];
    const float* meta_b    = (const float*)d_in[19];

    short*          ws    = (short*)d_ws;
    float*          poolf = (float*)((char*)d_ws + POOL_BYTE);
    float*          cntf  = (float*)((char*)d_ws + CNT_BYTE);
    float*          denf  = (float*)((char*)d_ws + DEN_BYTE);
    unsigned short* listb = (unsigned short*)((char*)d_ws + LIST_BYTE);
    int*            qcnt  = (int*)((char*)d_ws + QCNT_BYTE);
    float*          out   = (float*)d_out;

    prep_kernel<<<224, 512, 0, stream>>>(mlp_w1, mlp_w2, fuse_w1, fuse_w2, ws);
    scan_count<<<256, 256, 0, stream>>>(kinds, mask, cntf, denf, qcnt);
    scan_fill<<<256, 256, 0, stream>>>(kinds, mask, qcnt, listb);
    mlp_kernel<<<512, 512, 0, stream>>>(values, ws, listb, qcnt, B_ff, mlp_b1, poolf);
    fuse_kernel<<<256, 512, 0, stream>>>(ws, poolf, cntf, denf, prim_type, layer_id,
                                         meta, type_emb, layer_emb, mlp_b2, kind_emb,
                                         fuse_b1, fuse_b2, meta_w, meta_b, out);
}